// Round 11
// baseline (198.335 us; speedup 1.0000x reference)
//
#include <hip/hip_runtime.h>

constexpr int BS = 16;     // batch (vis and txt)
constexpr int S  = 4096;   // spatial
constexpr int E  = 128;    // embedding
constexpr int T  = 64;     // text tokens
constexpr int NSP = 4;     // s-quarters per (i,b) pair
constexpr int SSEG = S / NSP;        // 1024
constexpr int CH = 128;    // s-rows per chunk (8 waves x 16 rows)
constexpr int NCH = SSEG / CH;       // 8
constexpr int ETS = 136;   // ET stride (shorts): rows 16B-aligned, b128 reads bank-optimal
constexpr int TNS = 136;   // tnL stride (shorts)
constexpr int PTS = 72;    // prep transpose-tile stride (shorts): 144B rows, 16B-aligned

// ws layout:
//   shorts [0 .. 8388608)        : vn [b][s][e]  normalized bf16   (16 MB)
//   shorts [8388608 .. 16777216) : vnT[b][e][s]  normalized bf16   (16 MB)
//   floats [WS_P .. WS_P+8388608): wc^T partials [pair][quarter][e][t] (33.5 MB)
//   floats [WS_SIMS .. +256)     : sims[b*16+i]
constexpr long VN_OFF  = 0;
constexpr long VNT_OFF = (long)BS * S * E;
constexpr long WS_P    = (long)BS * S * E;              // float idx == byte 32 MB
constexpr long WS_SIMS = WS_P + (long)256 * NSP * 8192; // float idx

typedef __attribute__((ext_vector_type(8))) short bf16x8;
typedef __attribute__((ext_vector_type(4))) float f32x4;

__device__ __forceinline__ unsigned short f2bf(float x) {
    unsigned u = __float_as_uint(x);
    u += 0x7FFFu + ((u >> 16) & 1u);          // RTNE
    return (unsigned short)(u >> 16);
}
__device__ __forceinline__ float bf2f(unsigned short v) {
    return __uint_as_float(((unsigned)v) << 16);
}

// Pre-pass v3 (round-7 proven): two sequential 64-row halves, 18.4 KB LDS,
// 4 blocks/CU (32 waves/CU); at the ~25 us HBM floor for 160 MB.
__global__ __launch_bounds__(512, 4)
void prep_kernel(const float* __restrict__ vis, unsigned short* __restrict__ wsv)
{
    __shared__ unsigned short Lt[128 * PTS];   // 18.4 KB
    const int tid  = threadIdx.x;
    const int b    = blockIdx.x >> 5;
    const int tile = blockIdx.x & 31;
    const int s0   = tile * 128;
    const float* visb = vis + ((long)b * S + s0) * E;
    unsigned short* vn  = wsv + VN_OFF  + ((long)b * S + s0) * E;
    unsigned short* vnT = wsv + VNT_OFF + (long)b * E * S;

#pragma unroll
    for (int half = 0; half < 2; ++half) {
        if (half) __syncthreads();             // protect Lt reuse across halves
        {
            const int pp = tid >> 4, ee = tid & 15;     // pairs 0..31, lanes 0..15
            const int r  = (half << 6) + (pp << 1);     // row within tile
            const float* rA = visb + (long)r * E + (ee << 1);
            float2 va[4], vb[4];
            float sa = 0.f, sb = 0.f;
#pragma unroll
            for (int k = 0; k < 4; ++k) {
                va[k] = *(const float2*)(rA + (k << 5));
                vb[k] = *(const float2*)(rA + E + (k << 5));
                sa = fmaf(va[k].x, va[k].x, fmaf(va[k].y, va[k].y, sa));
                sb = fmaf(vb[k].x, vb[k].x, fmaf(vb[k].y, vb[k].y, sb));
            }
            sa += __shfl_xor(sa, 1); sa += __shfl_xor(sa, 2);
            sa += __shfl_xor(sa, 4); sa += __shfl_xor(sa, 8);
            sb += __shfl_xor(sb, 1); sb += __shfl_xor(sb, 2);
            sb += __shfl_xor(sb, 4); sb += __shfl_xor(sb, 8);
            const float ia = 1.0f / fmaxf(sqrtf(sa), 1e-12f);
            const float ib = 1.0f / fmaxf(sqrtf(sb), 1e-12f);
            const long r0 = (long)r * E, r1 = r0 + E;
#pragma unroll
            for (int k = 0; k < 4; ++k) {
                const int e0 = (ee << 1) + (k << 5);
                const unsigned ax = f2bf(va[k].x * ia), ay = f2bf(va[k].y * ia);
                const unsigned bx = f2bf(vb[k].x * ib), by = f2bf(vb[k].y * ib);
                *(unsigned*)&Lt[e0 * PTS + (pp << 1)]       = ax | (bx << 16);
                *(unsigned*)&Lt[(e0 + 1) * PTS + (pp << 1)] = ay | (by << 16);
                *(unsigned*)&vn[r0 + e0] = ax | (ay << 16);
                *(unsigned*)&vn[r1 + e0] = bx | (by << 16);
            }
        }
        __syncthreads();
        {
            const int e = tid >> 2, sg = tid & 3;
#pragma unroll
            for (int j = 0; j < 2; ++j) {
                const bf16x8 v = *(const bf16x8*)&Lt[e * PTS + (sg << 4) + (j << 3)];
                *(bf16x8*)&vnT[(long)e * S + s0 + (half << 6) + (sg << 4) + (j << 3)] = v;
            }
        }
    }
}

// Main: 1024 blocks = (i,b) x s-quarter. 512 threads = 8 waves. Round-0 EXACT —
// eight structural variants (R1,R2,R3,R4,R6,R9,R10 + pairing) all regressed;
// this interleave is the verified source-level floor (~100 us, latency-bound,
// no pipe >30%).
__global__ __launch_bounds__(512, 4)
void clip_main_kernel(const unsigned short* __restrict__ wsv,
                      const float* __restrict__ txt,
                      float* __restrict__ d_out,
                      float* __restrict__ wsf)
{
    __shared__ unsigned short ET[T * ETS];     // 17.4 KB
    __shared__ unsigned short tnL[T * TNS];    // 17.4 KB

    const int tid = threadIdx.x;
    const int w   = tid >> 6;       // wave 0..7
    const int l   = tid & 63;
    const int cl  = l & 15;
    const int q   = l >> 4;
    const int b   = blockIdx.x & 15;
    const int i   = (blockIdx.x >> 4) & 15;
    const int qt  = blockIdx.x >> 8;          // s-quarter 0..3
    const bool diag = (i == b);

    // ---- stage tn (normalized bf16) into LDS: row=tid>>3, 16-e seg=tid&7 ----
    {
        const int r = tid >> 3, seg = tid & 7;
        const float* tp = txt + ((long)i * T + r) * E + (seg << 4);
        const float4 a0 = *(const float4*)(tp);
        const float4 a1 = *(const float4*)(tp + 4);
        const float4 a2 = *(const float4*)(tp + 8);
        const float4 a3 = *(const float4*)(tp + 12);
        float ssq = a0.x*a0.x + a0.y*a0.y + a0.z*a0.z + a0.w*a0.w
                  + a1.x*a1.x + a1.y*a1.y + a1.z*a1.z + a1.w*a1.w
                  + a2.x*a2.x + a2.y*a2.y + a2.z*a2.z + a2.w*a2.w
                  + a3.x*a3.x + a3.y*a3.y + a3.z*a3.z + a3.w*a3.w;
        ssq += __shfl_xor(ssq, 1); ssq += __shfl_xor(ssq, 2); ssq += __shfl_xor(ssq, 4);
        const float inv = 1.0f / fmaxf(sqrtf(ssq), 1e-12f);
        bf16x8 f0, f1;
        f0[0]=(short)f2bf(a0.x*inv); f0[1]=(short)f2bf(a0.y*inv);
        f0[2]=(short)f2bf(a0.z*inv); f0[3]=(short)f2bf(a0.w*inv);
        f0[4]=(short)f2bf(a1.x*inv); f0[5]=(short)f2bf(a1.y*inv);
        f0[6]=(short)f2bf(a1.z*inv); f0[7]=(short)f2bf(a1.w*inv);
        f1[0]=(short)f2bf(a2.x*inv); f1[1]=(short)f2bf(a2.y*inv);
        f1[2]=(short)f2bf(a2.z*inv); f1[3]=(short)f2bf(a2.w*inv);
        f1[4]=(short)f2bf(a3.x*inv); f1[5]=(short)f2bf(a3.y*inv);
        f1[6]=(short)f2bf(a3.z*inv); f1[7]=(short)f2bf(a3.w*inv);
        *(bf16x8*)&tnL[r * TNS + (seg << 4)]     = f0;
        *(bf16x8*)&tnL[r * TNS + (seg << 4) + 8] = f1;
    }
    __syncthreads();

    f32x4 acc2[4];   // wc^T: e = w*16+q*4+r, t = n*16+cl
#pragma unroll
    for (int n = 0; n < 4; ++n) acc2[n] = (f32x4){0.f,0.f,0.f,0.f};

    const unsigned short* vnb  = wsv + VN_OFF  + (long)b * S * E;
    const unsigned short* vntb = wsv + VNT_OFF + (long)b * E * S;
    float* attb = d_out + 1 + (long)b * (long)T * S;

    for (int ch = 0; ch < NCH; ++ch) {
        const int s0 = qt * SSEG + ch * CH;

        // ---- GEMM1 B-loads (global bf16, L2-hot) ----
        bf16x8 Bf[4];
        {
            const unsigned short* r0 = vnb + (long)(s0 + (w << 4) + cl) * E + (q << 3);
#pragma unroll
            for (int kk = 0; kk < 4; ++kk) Bf[kk] = *(const bf16x8*)(r0 + (kk << 5));
        }

        // ---- GEMM1 (A from LDS) + softmax -> ET ----
        {
            f32x4 acc1[4];
#pragma unroll
            for (int mt = 0; mt < 4; ++mt) acc1[mt] = (f32x4){0.f,0.f,0.f,0.f};
#pragma unroll
            for (int kk = 0; kk < 4; ++kk)
#pragma unroll
                for (int mt = 0; mt < 4; ++mt) {
                    const bf16x8 tA = *(const bf16x8*)&tnL[((mt << 4) + cl) * TNS + (kk << 5) + (q << 3)];
                    acc1[mt] = __builtin_amdgcn_mfma_f32_16x16x32_bf16(tA, Bf[kk], acc1[mt], 0, 0, 0);
                }
            float ex[4][4];
            float ssum = 0.f;
#pragma unroll
            for (int mt = 0; mt < 4; ++mt)
#pragma unroll
                for (int r = 0; r < 4; ++r) {
                    const float v = __expf(acc1[mt][r]);   // |logit| <= ~1: no max needed
                    ex[mt][r] = v; ssum += v;
                }
            ssum += __shfl_xor(ssum, 16);
            ssum += __shfl_xor(ssum, 32);
            const float csc = 4.0f / ssum;
            const int sloc = (w << 4) + cl;
#pragma unroll
            for (int mt = 0; mt < 4; ++mt)
#pragma unroll
                for (int r = 0; r < 4; ++r)
                    ET[((mt << 4) + (q << 2) + r) * ETS + sloc] = f2bf(__expf(ex[mt][r] * csc));
        }
        __syncthreads();

        // ---- GEMM2: wc^T += vnT (global b128) x ET (LDS b128) ----
        {
            const unsigned short* ar = vntb + (long)((w << 4) + cl) * S + s0 + (q << 3);
#pragma unroll
            for (int kk2 = 0; kk2 < 4; ++kk2) {
                const bf16x8 aV = *(const bf16x8*)(ar + (kk2 << 5));
#pragma unroll
                for (int n = 0; n < 4; ++n) {
                    const bf16x8 bE = *(const bf16x8*)&ET[((n << 4) + cl) * ETS + (kk2 << 5) + (q << 3)];
                    acc2[n] = __builtin_amdgcn_mfma_f32_16x16x32_bf16(aV, bE, acc2[n], 0, 0, 0);
                }
            }
        }

        // ---- diag: dump unnormalized e (att_norm self-normalizes) ----
        if (diag) {
            const int t = tid >> 3, sg = (tid & 7) << 4;
            float* ap = attb + (long)t * S + s0 + sg;
            const bf16x8 v0 = *(const bf16x8*)&ET[t * ETS + sg];
            const bf16x8 v1 = *(const bf16x8*)&ET[t * ETS + sg + 8];
#pragma unroll
            for (int j = 0; j < 8; ++j) {
                ap[j]     = bf2f((unsigned short)v0[j]);
                ap[8 + j] = bf2f((unsigned short)v1[j]);
            }
        }
        __syncthreads();
    }

    // ---- store wc^T partials (disjoint per (pair, quarter) — no atomics) ----
    {
        float* pp = wsf + WS_P + ((long)(((i << 4) + b) << 2) + qt) * 8192;
#pragma unroll
        for (int n = 0; n < 4; ++n)
#pragma unroll
            for (int r = 0; r < 4; ++r)
                pp[((w << 4) + (q << 2) + r) * 64 + (n << 4) + cl] = acc2[n][r];
    }
}

// Post-pass v3: round-8 structure + loss FUSED via last-block pattern.
// Reduce blocks (0..255) write sims with device-scope atomicExch, then bump a
// counter in d_out[0] (zeroed by a 4-byte memsetAsync before launch). The 256th
// block to finish computes the 16x16 symmetric CE and overwrites d_out[0] with
// the loss. No spin-wait -> deadlock-free; all cross-XCD traffic goes through
// the coherent atomic path (G16).
__global__ __launch_bounds__(1024, 2)
void post_kernel(float* __restrict__ d_out, const float* __restrict__ txt,
                 float* __restrict__ wsf)
{
    const int tid = threadIdx.x;
    if (blockIdx.x < BS * BS) {
        // ---- reduce pair: 16 e-groups x 8 e, t = tid & 63 ----
        __shared__ float sA[1024], sB[1024], sC[1024];
        __shared__ bool lastFlag;
        const int pair = blockIdx.x;
        const int t = tid & 63, g = tid >> 6;          // g = 0..15
        const int i = pair >> 4, b = pair & 15;
        const float* p0 = wsf + WS_P + (long)pair * NSP * 8192;
        const float* tp = txt + ((long)i * T + t) * E + (g << 3);

        float ssq = 0.f, num = 0.f, w2 = 0.f;
#pragma unroll
        for (int e = 0; e < 8; ++e) {
            const float tv = tp[e];
            const int idx = ((g << 3) + e) * 64 + t;
            const float wc = p0[idx] + p0[idx + 8192] + p0[idx + 16384] + p0[idx + 24576];
            ssq = fmaf(tv, tv, ssq);
            num = fmaf(wc, tv, num);
            w2  = fmaf(wc, wc, w2);
        }
        sA[tid] = ssq; sB[tid] = num; sC[tid] = w2;
        __syncthreads();
        if (tid < 64) {
            float ss = 0.f, nm = 0.f, ww = 0.f;
#pragma unroll
            for (int k = 0; k < 16; ++k) {
                ss += sA[(k << 6) + tid];
                nm += sB[(k << 6) + tid];
                ww += sC[(k << 6) + tid];
            }
            const float cosv = (nm / fmaxf(sqrtf(ss), 1e-12f)) / fmaxf(sqrtf(ww), 1e-20f);
            float r = __expf(5.0f * cosv);
#pragma unroll
            for (int m = 1; m < 64; m <<= 1) r += __shfl_xor(r, m);
            if (tid == 0) {
                atomicExch(&wsf[WS_SIMS + (b << 4) + i], 10.0f * logf(r));
                __threadfence();
                const unsigned prev = atomicAdd((unsigned*)d_out, 1u);
                lastFlag = (prev == (unsigned)(BS * BS - 1));
            }
        }
        __syncthreads();
        if (!lastFlag) return;

        // ---- fused loss: this is the last reduce block; all sims are visible ----
        __threadfence();
        __shared__ float sm[16][17];
        __shared__ float red[16];
        const int bb = tid >> 4, ii = tid & 15;
        float lsm0 = 0.f;
        if (tid < 256) {
            const float x = atomicAdd(&wsf[WS_SIMS + bb * 16 + ii], 0.0f);
            sm[bb][ii] = x;
            float m = x;
#pragma unroll
            for (int msk = 1; msk < 16; msk <<= 1) m = fmaxf(m, __shfl_xor(m, msk));
            float s = __expf(x - m);
#pragma unroll
            for (int msk = 1; msk < 16; msk <<= 1) s += __shfl_xor(s, msk);
            lsm0 = x - m - logf(s);
        }
        __syncthreads();
        if (tid < 256) {
            const float y = sm[ii][bb];
            float m1 = y;
#pragma unroll
            for (int msk = 1; msk < 16; msk <<= 1) m1 = fmaxf(m1, __shfl_xor(m1, msk));
            float s1 = __expf(y - m1);
#pragma unroll
            for (int msk = 1; msk < 16; msk <<= 1) s1 += __shfl_xor(s1, msk);
            const float lsm1 = y - m1 - logf(s1);
            if (bb == ii) red[bb] = lsm0 + lsm1;
        }
        __syncthreads();
        if (tid == 0) {
            float tot = 0.f;
#pragma unroll
            for (int k = 0; k < 16; ++k) tot += red[k];
            d_out[0] = -tot / 32.0f;
        }
        return;
    }
    // ---- att row (b,t): self-normalize in place, one float4/thread ----
    __shared__ float r16[16];
    const int bt = blockIdx.x - BS * BS;
    float4* p4 = (float4*)(d_out + 1 + (long)bt * 4096);
    float4 v = p4[tid];
    float s = v.x + v.y + v.z + v.w;
#pragma unroll
    for (int m = 1; m < 64; m <<= 1) s += __shfl_xor(s, m);
    if ((tid & 63) == 0) r16[tid >> 6] = s;
    __syncthreads();
    float tot = 0.f;
#pragma unroll
    for (int k = 0; k < 16; ++k) tot += r16[k];
    const float inv = 1.0f / tot;
    v.x *= inv; v.y *= inv; v.z *= inv; v.w *= inv;
    p4[tid] = v;
}

extern "C" void kernel_launch(void* const* d_in, const int* in_sizes, int n_in,
                              void* d_out, int out_size, void* d_ws, size_t ws_size,
                              hipStream_t stream)
{
    const float* vis = (const float*)d_in[0];
    const float* txt = (const float*)d_in[1];
    float* out = (float*)d_out;
    unsigned short* wsv = (unsigned short*)d_ws;
    float* wsf = (float*)d_ws;

    hipLaunchKernelGGL(prep_kernel, dim3(512), dim3(512), 0, stream, vis, wsv);
    hipLaunchKernelGGL(clip_main_kernel, dim3(BS * BS * NSP), dim3(512), 0, stream,
                       wsv, txt, out, wsf);
    hipMemsetAsync(d_out, 0, 4, stream);   // zero the last-block counter (d_out[0])
    hipLaunchKernelGGL(post_kernel, dim3(BS * BS + BS * T), dim3(1024), 0, stream,
                       out, txt, wsf);
}

// Round 12
// 185.839 us; speedup vs baseline: 1.0672x; 1.0672x over previous
//
#include <hip/hip_runtime.h>

constexpr int BS = 16;     // batch (vis and txt)
constexpr int S  = 4096;   // spatial
constexpr int E  = 128;    // embedding
constexpr int T  = 64;     // text tokens
constexpr int NSP = 4;     // s-quarters per (i,b) pair
constexpr int SSEG = S / NSP;        // 1024
constexpr int CH = 128;    // s-rows per chunk (8 waves x 16 rows)
constexpr int NCH = SSEG / CH;       // 8
constexpr int ETS = 136;   // ET stride (shorts): rows 16B-aligned, b128 reads bank-optimal
constexpr int TNS = 136;   // tnL stride (shorts)
constexpr int PTS = 72;    // prep transpose-tile stride (shorts): 144B rows, 16B-aligned

// ws layout:
//   shorts [0 .. 8388608)        : vn [b][s][e]  normalized bf16   (16 MB)
//   shorts [8388608 .. 16777216) : vnT[b][e][s]  normalized bf16   (16 MB)
//   floats [WS_P .. WS_P+8388608): wc^T partials [pair][quarter][e][t] (33.5 MB)
//   floats [WS_SIMS .. +256)     : sims[b*16+i]
constexpr long VN_OFF  = 0;
constexpr long VNT_OFF = (long)BS * S * E;
constexpr long WS_P    = (long)BS * S * E;              // float idx == byte 32 MB
constexpr long WS_SIMS = WS_P + (long)256 * NSP * 8192; // float idx

typedef __attribute__((ext_vector_type(8))) short bf16x8;
typedef __attribute__((ext_vector_type(4))) float f32x4;

__device__ __forceinline__ unsigned short f2bf(float x) {
    unsigned u = __float_as_uint(x);
    u += 0x7FFFu + ((u >> 16) & 1u);          // RTNE
    return (unsigned short)(u >> 16);
}
__device__ __forceinline__ float bf2f(unsigned short v) {
    return __uint_as_float(((unsigned)v) << 16);
}

// Pre-pass v3 (round-7 proven): two sequential 64-row halves, 18.4 KB LDS,
// 4 blocks/CU (32 waves/CU); near the ~25-30 us HBM floor for 160 MB.
__global__ __launch_bounds__(512, 4)
void prep_kernel(const float* __restrict__ vis, unsigned short* __restrict__ wsv)
{
    __shared__ unsigned short Lt[128 * PTS];   // 18.4 KB
    const int tid  = threadIdx.x;
    const int b    = blockIdx.x >> 5;
    const int tile = blockIdx.x & 31;
    const int s0   = tile * 128;
    const float* visb = vis + ((long)b * S + s0) * E;
    unsigned short* vn  = wsv + VN_OFF  + ((long)b * S + s0) * E;
    unsigned short* vnT = wsv + VNT_OFF + (long)b * E * S;

#pragma unroll
    for (int half = 0; half < 2; ++half) {
        if (half) __syncthreads();             // protect Lt reuse across halves
        {
            const int pp = tid >> 4, ee = tid & 15;     // pairs 0..31, lanes 0..15
            const int r  = (half << 6) + (pp << 1);     // row within tile
            const float* rA = visb + (long)r * E + (ee << 1);
            float2 va[4], vb[4];
            float sa = 0.f, sb = 0.f;
#pragma unroll
            for (int k = 0; k < 4; ++k) {
                va[k] = *(const float2*)(rA + (k << 5));
                vb[k] = *(const float2*)(rA + E + (k << 5));
                sa = fmaf(va[k].x, va[k].x, fmaf(va[k].y, va[k].y, sa));
                sb = fmaf(vb[k].x, vb[k].x, fmaf(vb[k].y, vb[k].y, sb));
            }
            sa += __shfl_xor(sa, 1); sa += __shfl_xor(sa, 2);
            sa += __shfl_xor(sa, 4); sa += __shfl_xor(sa, 8);
            sb += __shfl_xor(sb, 1); sb += __shfl_xor(sb, 2);
            sb += __shfl_xor(sb, 4); sb += __shfl_xor(sb, 8);
            const float ia = 1.0f / fmaxf(sqrtf(sa), 1e-12f);
            const float ib = 1.0f / fmaxf(sqrtf(sb), 1e-12f);
            const long r0 = (long)r * E, r1 = r0 + E;
#pragma unroll
            for (int k = 0; k < 4; ++k) {
                const int e0 = (ee << 1) + (k << 5);
                const unsigned ax = f2bf(va[k].x * ia), ay = f2bf(va[k].y * ia);
                const unsigned bx = f2bf(vb[k].x * ib), by = f2bf(vb[k].y * ib);
                *(unsigned*)&Lt[e0 * PTS + (pp << 1)]       = ax | (bx << 16);
                *(unsigned*)&Lt[(e0 + 1) * PTS + (pp << 1)] = ay | (by << 16);
                *(unsigned*)&vn[r0 + e0] = ax | (ay << 16);
                *(unsigned*)&vn[r1 + e0] = bx | (by << 16);
            }
        }
        __syncthreads();
        {
            const int e = tid >> 2, sg = tid & 3;
#pragma unroll
            for (int j = 0; j < 2; ++j) {
                const bf16x8 v = *(const bf16x8*)&Lt[e * PTS + (sg << 4) + (j << 3)];
                *(bf16x8*)&vnT[(long)e * S + s0 + (half << 6) + (sg << 4) + (j << 3)] = v;
            }
        }
    }
}

// Main: 1024 blocks = (i,b) x s-quarter. 512 threads = 8 waves. Round-0 EXACT —
// nine structural variants all regressed; this interleave is the verified
// source-level floor (~100 us, latency-bound, no pipe >30%).
__global__ __launch_bounds__(512, 4)
void clip_main_kernel(const unsigned short* __restrict__ wsv,
                      const float* __restrict__ txt,
                      float* __restrict__ d_out,
                      float* __restrict__ wsf)
{
    __shared__ unsigned short ET[T * ETS];     // 17.4 KB
    __shared__ unsigned short tnL[T * TNS];    // 17.4 KB

    const int tid = threadIdx.x;
    const int w   = tid >> 6;       // wave 0..7
    const int l   = tid & 63;
    const int cl  = l & 15;
    const int q   = l >> 4;
    const int b   = blockIdx.x & 15;
    const int i   = (blockIdx.x >> 4) & 15;
    const int qt  = blockIdx.x >> 8;          // s-quarter 0..3
    const bool diag = (i == b);

    // ---- stage tn (normalized bf16) into LDS: row=tid>>3, 16-e seg=tid&7 ----
    {
        const int r = tid >> 3, seg = tid & 7;
        const float* tp = txt + ((long)i * T + r) * E + (seg << 4);
        const float4 a0 = *(const float4*)(tp);
        const float4 a1 = *(const float4*)(tp + 4);
        const float4 a2 = *(const float4*)(tp + 8);
        const float4 a3 = *(const float4*)(tp + 12);
        float ssq = a0.x*a0.x + a0.y*a0.y + a0.z*a0.z + a0.w*a0.w
                  + a1.x*a1.x + a1.y*a1.y + a1.z*a1.z + a1.w*a1.w
                  + a2.x*a2.x + a2.y*a2.y + a2.z*a2.z + a2.w*a2.w
                  + a3.x*a3.x + a3.y*a3.y + a3.z*a3.z + a3.w*a3.w;
        ssq += __shfl_xor(ssq, 1); ssq += __shfl_xor(ssq, 2); ssq += __shfl_xor(ssq, 4);
        const float inv = 1.0f / fmaxf(sqrtf(ssq), 1e-12f);
        bf16x8 f0, f1;
        f0[0]=(short)f2bf(a0.x*inv); f0[1]=(short)f2bf(a0.y*inv);
        f0[2]=(short)f2bf(a0.z*inv); f0[3]=(short)f2bf(a0.w*inv);
        f0[4]=(short)f2bf(a1.x*inv); f0[5]=(short)f2bf(a1.y*inv);
        f0[6]=(short)f2bf(a1.z*inv); f0[7]=(short)f2bf(a1.w*inv);
        f1[0]=(short)f2bf(a2.x*inv); f1[1]=(short)f2bf(a2.y*inv);
        f1[2]=(short)f2bf(a2.z*inv); f1[3]=(short)f2bf(a2.w*inv);
        f1[4]=(short)f2bf(a3.x*inv); f1[5]=(short)f2bf(a3.y*inv);
        f1[6]=(short)f2bf(a3.z*inv); f1[7]=(short)f2bf(a3.w*inv);
        *(bf16x8*)&tnL[r * TNS + (seg << 4)]     = f0;
        *(bf16x8*)&tnL[r * TNS + (seg << 4) + 8] = f1;
    }
    __syncthreads();

    f32x4 acc2[4];   // wc^T: e = w*16+q*4+r, t = n*16+cl
#pragma unroll
    for (int n = 0; n < 4; ++n) acc2[n] = (f32x4){0.f,0.f,0.f,0.f};

    const unsigned short* vnb  = wsv + VN_OFF  + (long)b * S * E;
    const unsigned short* vntb = wsv + VNT_OFF + (long)b * E * S;
    float* attb = d_out + 1 + (long)b * (long)T * S;

    for (int ch = 0; ch < NCH; ++ch) {
        const int s0 = qt * SSEG + ch * CH;

        // ---- GEMM1 B-loads (global bf16, L2-hot) ----
        bf16x8 Bf[4];
        {
            const unsigned short* r0 = vnb + (long)(s0 + (w << 4) + cl) * E + (q << 3);
#pragma unroll
            for (int kk = 0; kk < 4; ++kk) Bf[kk] = *(const bf16x8*)(r0 + (kk << 5));
        }

        // ---- GEMM1 (A from LDS) + softmax -> ET ----
        {
            f32x4 acc1[4];
#pragma unroll
            for (int mt = 0; mt < 4; ++mt) acc1[mt] = (f32x4){0.f,0.f,0.f,0.f};
#pragma unroll
            for (int kk = 0; kk < 4; ++kk)
#pragma unroll
                for (int mt = 0; mt < 4; ++mt) {
                    const bf16x8 tA = *(const bf16x8*)&tnL[((mt << 4) + cl) * TNS + (kk << 5) + (q << 3)];
                    acc1[mt] = __builtin_amdgcn_mfma_f32_16x16x32_bf16(tA, Bf[kk], acc1[mt], 0, 0, 0);
                }
            float ex[4][4];
            float ssum = 0.f;
#pragma unroll
            for (int mt = 0; mt < 4; ++mt)
#pragma unroll
                for (int r = 0; r < 4; ++r) {
                    const float v = __expf(acc1[mt][r]);   // |logit| <= ~1: no max needed
                    ex[mt][r] = v; ssum += v;
                }
            ssum += __shfl_xor(ssum, 16);
            ssum += __shfl_xor(ssum, 32);
            const float csc = 4.0f / ssum;
            const int sloc = (w << 4) + cl;
#pragma unroll
            for (int mt = 0; mt < 4; ++mt)
#pragma unroll
                for (int r = 0; r < 4; ++r)
                    ET[((mt << 4) + (q << 2) + r) * ETS + sloc] = f2bf(__expf(ex[mt][r] * csc));
        }
        __syncthreads();

        // ---- GEMM2: wc^T += vnT (global b128) x ET (LDS b128) ----
        {
            const unsigned short* ar = vntb + (long)((w << 4) + cl) * S + s0 + (q << 3);
#pragma unroll
            for (int kk2 = 0; kk2 < 4; ++kk2) {
                const bf16x8 aV = *(const bf16x8*)(ar + (kk2 << 5));
#pragma unroll
                for (int n = 0; n < 4; ++n) {
                    const bf16x8 bE = *(const bf16x8*)&ET[((n << 4) + cl) * ETS + (kk2 << 5) + (q << 3)];
                    acc2[n] = __builtin_amdgcn_mfma_f32_16x16x32_bf16(aV, bE, acc2[n], 0, 0, 0);
                }
            }
        }

        // ---- diag: dump unnormalized e (att_norm self-normalizes) ----
        if (diag) {
            const int t = tid >> 3, sg = (tid & 7) << 4;
            float* ap = attb + (long)t * S + s0 + sg;
            const bf16x8 v0 = *(const bf16x8*)&ET[t * ETS + sg];
            const bf16x8 v1 = *(const bf16x8*)&ET[t * ETS + sg + 8];
#pragma unroll
            for (int j = 0; j < 8; ++j) {
                ap[j]     = bf2f((unsigned short)v0[j]);
                ap[8 + j] = bf2f((unsigned short)v1[j]);
            }
        }
        __syncthreads();
    }

    // ---- store wc^T partials (disjoint per (pair, quarter) — no atomics) ----
    {
        float* pp = wsf + WS_P + ((long)(((i << 4) + b) << 2) + qt) * 8192;
#pragma unroll
        for (int n = 0; n < 4; ++n)
#pragma unroll
            for (int r = 0; r < 4; ++r)
                pp[((w << 4) + (q << 2) + r) * 64 + (n << 4) + cl] = acc2[n][r];
    }
}

// Post-pass v2 (round-8 proven): 1024 threads/block. Blocks 0..255 = pair-reduce
// FIRST (the long pole: 33.5 MB latency-bound stream; 16 waves/block, dispatched
// before the att blocks so it overlaps them). Blocks 256..1279 = att row
// self-normalize, one float4 per thread.
__global__ __launch_bounds__(1024, 2)
void post_kernel(float* __restrict__ d_out, const float* __restrict__ txt,
                 float* __restrict__ wsf)
{
    const int tid = threadIdx.x;
    if (blockIdx.x < BS * BS) {
        // ---- reduce pair: 16 e-groups x 8 e, t = tid & 63 ----
        __shared__ float sA[1024], sB[1024], sC[1024];
        const int pair = blockIdx.x;
        const int t = tid & 63, g = tid >> 6;          // g = 0..15
        const int i = pair >> 4, b = pair & 15;
        const float* p0 = wsf + WS_P + (long)pair * NSP * 8192;
        const float* tp = txt + ((long)i * T + t) * E + (g << 3);

        float ssq = 0.f, num = 0.f, w2 = 0.f;
#pragma unroll
        for (int e = 0; e < 8; ++e) {
            const float tv = tp[e];
            const int idx = ((g << 3) + e) * 64 + t;
            const float wc = p0[idx] + p0[idx + 8192] + p0[idx + 16384] + p0[idx + 24576];
            ssq = fmaf(tv, tv, ssq);
            num = fmaf(wc, tv, num);
            w2  = fmaf(wc, wc, w2);
        }
        sA[tid] = ssq; sB[tid] = num; sC[tid] = w2;
        __syncthreads();
        if (tid < 64) {
            float ss = 0.f, nm = 0.f, ww = 0.f;
#pragma unroll
            for (int k = 0; k < 16; ++k) {
                ss += sA[(k << 6) + tid];
                nm += sB[(k << 6) + tid];
                ww += sC[(k << 6) + tid];
            }
            const float cosv = (nm / fmaxf(sqrtf(ss), 1e-12f)) / fmaxf(sqrtf(ww), 1e-20f);
            float r = __expf(5.0f * cosv);
#pragma unroll
            for (int m = 1; m < 64; m <<= 1) r += __shfl_xor(r, m);
            if (tid == 0) wsf[WS_SIMS + (b << 4) + i] = 10.0f * logf(r);
        }
        return;
    }
    // ---- att row (b,t): self-normalize in place, one float4/thread ----
    __shared__ float r16[16];
    const int bt = blockIdx.x - BS * BS;
    float4* p4 = (float4*)(d_out + 1 + (long)bt * 4096);
    float4 v = p4[tid];
    float s = v.x + v.y + v.z + v.w;
#pragma unroll
    for (int m = 1; m < 64; m <<= 1) s += __shfl_xor(s, m);
    if ((tid & 63) == 0) r16[tid >> 6] = s;
    __syncthreads();
    float tot = 0.f;
#pragma unroll
    for (int k = 0; k < 16; ++k) tot += r16[k];
    const float inv = 1.0f / tot;
    v.x *= inv; v.y *= inv; v.z *= inv; v.w *= inv;
    p4[tid] = v;
}

// Final 16x16 symmetric cross-entropy (needs all sims -> separate launch;
// fusing it into post_kernel via last-block pattern REGRESSED +10 us, R11).
__global__ __launch_bounds__(256, 1)
void loss_kernel(const float* __restrict__ wsf, float* __restrict__ d_out)
{
    __shared__ float sm[16][17];
    __shared__ float red[16];
    const int tid = threadIdx.x;
    const int bb = tid >> 4, ii = tid & 15;
    const float x = wsf[WS_SIMS + bb * 16 + ii];
    sm[bb][ii] = x;
    float m = x;
#pragma unroll
    for (int msk = 1; msk < 16; msk <<= 1) m = fmaxf(m, __shfl_xor(m, msk));
    float s = __expf(x - m);
#pragma unroll
    for (int msk = 1; msk < 16; msk <<= 1) s += __shfl_xor(s, msk);
    const float lsm0 = x - m - logf(s);
    __syncthreads();
    const float y = sm[ii][bb];
    float m1 = y;
#pragma unroll
    for (int msk = 1; msk < 16; msk <<= 1) m1 = fmaxf(m1, __shfl_xor(m1, msk));
    float s1 = __expf(y - m1);
#pragma unroll
    for (int msk = 1; msk < 16; msk <<= 1) s1 += __shfl_xor(s1, msk);
    const float lsm1 = y - m1 - logf(s1);
    if (bb == ii) red[bb] = lsm0 + lsm1;
    __syncthreads();
    if (tid == 0) {
        float tot = 0.f;
#pragma unroll
        for (int k = 0; k < 16; ++k) tot += red[k];
        d_out[0] = -tot / 32.0f;
    }
}

extern "C" void kernel_launch(void* const* d_in, const int* in_sizes, int n_in,
                              void* d_out, int out_size, void* d_ws, size_t ws_size,
                              hipStream_t stream)
{
    const float* vis = (const float*)d_in[0];
    const float* txt = (const float*)d_in[1];
    float* out = (float*)d_out;
    unsigned short* wsv = (unsigned short*)d_ws;
    float* wsf = (float*)d_ws;

    hipLaunchKernelGGL(prep_kernel, dim3(512), dim3(512), 0, stream, vis, wsv);
    hipLaunchKernelGGL(clip_main_kernel, dim3(BS * BS * NSP), dim3(512), 0, stream,
                       wsv, txt, out, wsf);
    hipLaunchKernelGGL(post_kernel, dim3(BS * BS + BS * T), dim3(1024), 0, stream,
                       out, txt, wsf);
    hipLaunchKernelGGL(loss_kernel, dim3(1), dim3(256), 0, stream, wsf, out);
}